// Round 1
// baseline (1274.619 us; speedup 1.0000x reference)
//
#include <hip/hip_runtime.h>
#include <float.h>

// Problem constants (match reference)
#define K_NN 8
#define NS 12
#define NG 6
#define NBLOCK 3
#define HEADS 2
#define BB 2
#define NPTS 4096
#define NN (BB*NPTS)     // 8192 total nodes
#define NF 14            // 2 + NS features in d1

__device__ __forceinline__ float lrelu(float x) { return x >= 0.f ? x : 0.2f * x; }

// ---------------------------------------------------------------------------
// KNN: one wave (64 lanes) per row; 4 rows per 256-thread block.
// dist = d2[n] + d2[m] - 2*dot(x_n, x_m), self skipped (reference adds 1e9).
// Tie-break: smaller distance first, then smaller index (jax.lax.top_k).
// Per-lane top-8 kept in registers with STATIC-index bubble insertion
// (dynamic indexing would spill to scratch). Merge via 8 rounds of
// lexicographic wave-argmin butterflies.
// ---------------------------------------------------------------------------
__global__ __launch_bounds__(256) void knn_kernel(const float* __restrict__ d1c,
                                                  int* __restrict__ idxo) {
  const int rb = blockIdx.x;               // 0 .. B*N/4-1
  const int b = rb / (NPTS / 4);
  const int n0 = (rb % (NPTS / 4)) * 4;
  const int wave = threadIdx.x >> 6;
  const int lane = threadIdx.x & 63;
  const int n = n0 + wave;                 // local row in this batch
  const float* X = d1c + (size_t)b * NPTS * NF;

  float xr[NF];
#pragma unroll
  for (int f = 0; f < NF; ++f) xr[f] = X[n * NF + f];
  float d2n = 0.f;
#pragma unroll
  for (int f = 0; f < NF; ++f) d2n += xr[f] * xr[f];

  float bd[8]; int bi[8];
#pragma unroll
  for (int p = 0; p < 8; ++p) { bd[p] = FLT_MAX; bi[p] = 0x7fffffff; }

  __shared__ float tile[256 * NF];
  for (int t0 = 0; t0 < NPTS; t0 += 256) {
    __syncthreads();
    for (int ii = threadIdx.x; ii < 256 * NF; ii += 256) tile[ii] = X[t0 * NF + ii];
    __syncthreads();
#pragma unroll
    for (int cc = 0; cc < 4; ++cc) {
      const int c = cc * 64 + lane;
      const int m = t0 + c;
      float dot = 0.f, ss = 0.f;
#pragma unroll
      for (int f = 0; f < NF; ++f) {
        float v = tile[c * NF + f];
        dot += xr[f] * v;
        ss  += v * v;
      }
      float dist = d2n + ss - 2.0f * dot;
      if (m != n) {
        if (dist < bd[7] || (dist == bd[7] && m < bi[7])) {
          float cd = dist; int ci = m;
#pragma unroll
          for (int p = 0; p < 8; ++p) {
            bool lt = (cd < bd[p]) || (cd == bd[p] && ci < bi[p]);
            if (lt) { float td = bd[p]; int ti = bi[p]; bd[p] = cd; bi[p] = ci; cd = td; ci = ti; }
          }
        }
      }
    }
  }

  // Merge 64 sorted 8-lists -> global top-8 (8 extraction rounds)
  const size_t obase = ((size_t)b * NPTS + n) * K_NN;
#pragma unroll 1
  for (int r = 0; r < K_NN; ++r) {
    float hv = bd[0]; int hi = bi[0];
    float v = hv; int vi = hi;
#pragma unroll
    for (int off = 32; off > 0; off >>= 1) {
      float ov = __shfl_xor(v, off);
      int   oi = __shfl_xor(vi, off);
      if (ov < v || (ov == v && oi < vi)) { v = ov; vi = oi; }
    }
    if (lane == 0) idxo[obase + r] = b * NPTS + vi;   // store GLOBAL node index
    if (hi == vi) {                                    // unique winner pops its head
#pragma unroll
      for (int p = 0; p < 7; ++p) { bd[p] = bd[p + 1]; bi[p] = bi[p + 1]; }
      bd[7] = FLT_MAX; bi[7] = 0x7fffffff;
    }
  }
}

// ---------------------------------------------------------------------------
// GAT projection: h[n][hh][d] = sum_f x[n][f] * W[f][hh][d]; plus per-head
// src/dst attention dots. W, a_src, a_dst staged in LDS (broadcast reads).
// ---------------------------------------------------------------------------
template <int F, int DH>
__global__ __launch_bounds__(256) void proj_kernel(const float* __restrict__ x, int ldx,
                                                   const float* __restrict__ W,
                                                   const float* __restrict__ asrc,
                                                   const float* __restrict__ adst,
                                                   float* __restrict__ hout,
                                                   float* __restrict__ sdout) {
  __shared__ float Wl[F * 2 * DH];
  __shared__ float asl[2 * DH];
  __shared__ float adl[2 * DH];
  for (int i = threadIdx.x; i < F * 2 * DH; i += 256) Wl[i] = W[i];
  for (int i = threadIdx.x; i < 2 * DH; i += 256) { asl[i] = asrc[i]; adl[i] = adst[i]; }
  __syncthreads();

  const int n = blockIdx.x * 256 + threadIdx.x;
  if (n >= NN) return;

  float xv[F];
#pragma unroll
  for (int f = 0; f < F; ++f) xv[f] = x[(size_t)n * ldx + f];

  float h[2 * DH];
#pragma unroll
  for (int o = 0; o < 2 * DH; ++o) {
    float acc = 0.f;
#pragma unroll
    for (int f = 0; f < F; ++f) acc += xv[f] * Wl[f * 2 * DH + o];
    h[o] = acc;
  }
  float s0 = 0.f, s1 = 0.f, t0 = 0.f, t1 = 0.f;
#pragma unroll
  for (int d = 0; d < DH; ++d) { s0 += h[d] * asl[d];       t0 += h[d] * adl[d]; }
#pragma unroll
  for (int d = 0; d < DH; ++d) { s1 += h[DH + d] * asl[DH + d]; t1 += h[DH + d] * adl[DH + d]; }

#pragma unroll
  for (int o = 0; o < 2 * DH; ++o) hout[(size_t)n * 2 * DH + o] = h[o];
  float4 sd = make_float4(s0, s1, t0, t1);
  *(float4*)&sdout[(size_t)n * 4] = sd;
}

// ---------------------------------------------------------------------------
// GAT aggregation: per node, gather 8 neighbors, per-head softmax over k of
// lrelu(src_n + dst_j), y[d] = sum_{k,h} alpha * h_j / HEADS. Optional lrelu.
// ---------------------------------------------------------------------------
template <int DH, bool LR>
__global__ __launch_bounds__(256) void agg_kernel(const float* __restrict__ h,
                                                  const float* __restrict__ sd,
                                                  const int* __restrict__ idx,
                                                  float* __restrict__ yout) {
  const int n = blockIdx.x * 256 + threadIdx.x;
  if (n >= NN) return;

  const float4 s4 = *(const float4*)&sd[(size_t)n * 4];
  const float s0 = s4.x, s1 = s4.y;

  int jj[K_NN];
#pragma unroll
  for (int k = 0; k < K_NN; ++k) jj[k] = idx[(size_t)n * K_NN + k];

  float e0[K_NN], e1[K_NN];
#pragma unroll
  for (int k = 0; k < K_NN; ++k) {
    const float4 t4 = *(const float4*)&sd[(size_t)jj[k] * 4];
    e0[k] = lrelu(s0 + t4.z);
    e1[k] = lrelu(s1 + t4.w);
  }
  float m0 = -FLT_MAX, m1 = -FLT_MAX;
#pragma unroll
  for (int k = 0; k < K_NN; ++k) { m0 = fmaxf(m0, e0[k]); m1 = fmaxf(m1, e1[k]); }
  float w0[K_NN], w1[K_NN], S0 = 0.f, S1 = 0.f;
#pragma unroll
  for (int k = 0; k < K_NN; ++k) {
    w0[k] = __expf(e0[k] - m0); S0 += w0[k];
    w1[k] = __expf(e1[k] - m1); S1 += w1[k];
  }
  const float r0 = 0.5f / S0, r1 = 0.5f / S1;

  float y[DH];
#pragma unroll
  for (int d = 0; d < DH; ++d) y[d] = 0.f;
#pragma unroll
  for (int k = 0; k < K_NN; ++k) {
    const float* hj = h + (size_t)jj[k] * 2 * DH;
    const float a0 = w0[k] * r0, a1 = w1[k] * r1;
#pragma unroll
    for (int d = 0; d < DH; ++d) y[d] += a0 * hj[d] + a1 * hj[DH + d];
  }
#pragma unroll
  for (int d = 0; d < DH; ++d) yout[(size_t)n * DH + d] = LR ? lrelu(y[d]) : y[d];
}

// ---------------------------------------------------------------------------
// Gumbel hard-select: argmax(logits+g) (softmax is monotone; hard+y-y == hard
// to ~1 ulp). Writes x1,x2 to output slab + scratch; optionally |d - x| feats.
// ---------------------------------------------------------------------------
__global__ __launch_bounds__(256) void sel_kernel(const float* __restrict__ d1c,
                                                  const float* __restrict__ w1o,
                                                  const float* __restrict__ gum,
                                                  int blk, float* __restrict__ out,
                                                  float* __restrict__ x12,
                                                  float* __restrict__ x1f, int writeX1f) {
  const int n = blockIdx.x * 256 + threadIdx.x;
  if (n >= NN) return;
  const int b = n >> 12, nl = n & (NPTS - 1);
  const float* g1 = gum + (((size_t)(blk * 2 + 0) * BB + b) * NPTS + nl) * NG;
  const float* g2 = gum + (((size_t)(blk * 2 + 1) * BB + b) * NPTS + nl) * NG;
  const float* w = w1o + (size_t)n * NS;
  const float* dr = d1c + (size_t)n * NF;

  float best1 = -FLT_MAX, best2 = -FLT_MAX;
  int a1 = 0, a2 = 0;
#pragma unroll
  for (int a = 0; a < NG; ++a) {
    float l1 = w[2 * a] + g1[a];
    if (l1 > best1) { best1 = l1; a1 = a; }
    float l2 = w[2 * a + 1] + g2[a];
    if (l2 > best2) { best2 = l2; a2 = a; }
  }
  const float x1 = dr[2 + 2 * a1];
  const float x2 = dr[3 + 2 * a2];

  const size_t ob = (((size_t)blk * BB + b) * NPTS + nl) * 2;
  out[ob + 0] = x1;
  out[ob + 1] = x2;
  x12[n * 2 + 0] = x1;
  x12[n * 2 + 1] = x2;

  if (writeX1f) {
#pragma unroll
    for (int g = 0; g < NG; ++g) {
      x1f[(size_t)n * NS + 2 * g]     = fabsf(dr[2 + 2 * g] - x1);
      x1f[(size_t)n * NS + 2 * g + 1] = fabsf(dr[3 + 2 * g] - x2);
    }
  }
}

// ---------------------------------------------------------------------------
// d1 update: wbar = softmax([x_ws, d_ws]); d1[2+c] = w0*ch0[c] + w1*d1[2+c].
// ---------------------------------------------------------------------------
__global__ __launch_bounds__(256) void combine_kernel(float* __restrict__ d1c,
                                                      const float* __restrict__ xws,
                                                      const float* __restrict__ dws,
                                                      const float* __restrict__ x12) {
  const int n = blockIdx.x * 256 + threadIdx.x;
  if (n >= NN) return;
  const float x1 = x12[n * 2 + 0], x2 = x12[n * 2 + 1];
  float* dr = d1c + (size_t)n * NF;
  float nd[NS];
#pragma unroll
  for (int c = 0; c < NS; ++c) {
    const float a = xws[(size_t)n * NS + c];
    const float dd = dws[(size_t)n * NS + c];
    const float m = fmaxf(a, dd);
    const float ea = __expf(a - m), ed = __expf(dd - m);
    const float inv = 1.f / (ea + ed);
    const float ch0 = (c & 1) ? x2 : x1;
    nd[c] = (ea * inv) * ch0 + (ed * inv) * dr[2 + c];
  }
#pragma unroll
  for (int c = 0; c < NS; ++c) dr[2 + c] = nd[c];
}

// ---------------------------------------------------------------------------
extern "C" void kernel_launch(void* const* d_in, const int* in_sizes, int n_in,
                              void* d_out, int out_size, void* d_ws, size_t ws_size,
                              hipStream_t stream) {
  const float* d1_in = (const float*)d_in[0];
  const float* gum   = (const float*)d_in[1];
  const float* W1    = (const float*)d_in[2];
  const float* a1s   = (const float*)d_in[3];
  const float* a1d   = (const float*)d_in[4];
  const float* W2    = (const float*)d_in[5];
  const float* a2s   = (const float*)d_in[6];
  const float* a2d   = (const float*)d_in[7];
  float* out = (float*)d_out;

  // Workspace partition (floats). Total ~1.51M floats = ~6.0 MB.
  float* ws     = (float*)d_ws;
  float* d1c    = ws;                        // 8192*14   = 114688
  int*   idxb   = (int*)(ws + 114688);       // 8192*8    = 65536 ints
  float* hbuf   = ws + 114688 + 65536;       // 8192*64   = 524288
  float* sdb    = hbuf + 524288;             // 8192*4    = 32768
  float* ybuf   = sdb + 32768;               // 8192*32   = 262144
  float* feats  = ybuf + 262144;             // 8192*12   = 98304
  float* bufw1  = feats + 98304;             // 98304  (w1 logits / x_ws)
  float* bufxfi = bufw1 + 98304;             // 98304  (x1f_in)
  float* bufxf  = bufxfi + 98304;            // 98304  (xf)
  float* bufdws = bufxf + 98304;             // 98304  (d_ws)
  float* x12    = bufdws + 98304;            // 8192*2 = 16384

  hipMemcpyAsync(d1c, d1_in, (size_t)NN * NF * sizeof(float),
                 hipMemcpyDeviceToDevice, stream);

  const int NB = NN / 256;  // 32 blocks for node-parallel kernels

  auto run_fe = [&](const float* xin, int ldx, int m, float* yout, bool lrelu_out) {
    proj_kernel<12, 32><<<NB, 256, 0, stream>>>(xin, ldx, W1 + (size_t)m * 768,
                                                a1s + (size_t)m * 64, a1d + (size_t)m * 64,
                                                hbuf, sdb);
    agg_kernel<32, true><<<NB, 256, 0, stream>>>(hbuf, sdb, idxb, ybuf);
    proj_kernel<32, 12><<<NB, 256, 0, stream>>>(ybuf, 32, W2 + (size_t)m * 768,
                                                a2s + (size_t)m * 24, a2d + (size_t)m * 24,
                                                hbuf, sdb);
    if (lrelu_out)
      agg_kernel<12, true><<<NB, 256, 0, stream>>>(hbuf, sdb, idxb, yout);
    else
      agg_kernel<12, false><<<NB, 256, 0, stream>>>(hbuf, sdb, idxb, yout);
  };

  for (int i = 0; i < NBLOCK; ++i) {
    knn_kernel<<<BB * (NPTS / 4), 256, 0, stream>>>(d1c, idxb);
    run_fe(d1c + 2, NF, 2 * i, feats, true);          // feats = lrelu(fe(d1[:,2:]))
    run_fe(feats, NS, 2 * i + 1, bufw1, false);       // w1 logits
    sel_kernel<<<NB, 256, 0, stream>>>(d1c, bufw1, gum, i, out, x12, bufxfi,
                                       (i < NBLOCK - 1) ? 1 : 0);
    if (i == NBLOCK - 1) break;
    run_fe(bufxfi, NS, 6 + 3 * i, bufxf, true);       // xf = lrelu(fe(x1f_in))
    run_fe(bufxf, NS, 6 + 3 * i + 1, bufw1, false);   // x_ws
    run_fe(feats, NS, 6 + 3 * i + 2, bufdws, false);  // d_ws
    combine_kernel<<<NB, 256, 0, stream>>>(d1c, bufw1, bufdws, x12);
  }
}

// Round 3
// 1067.634 us; speedup vs baseline: 1.1939x; 1.1939x over previous
//
#include <hip/hip_runtime.h>
#include <float.h>

// Problem constants (match reference)
#define K_NN 8
#define NS 12
#define NG 6
#define NBLOCK 3
#define HEADS 2
#define BB 2
#define NPTS 4096
#define NN (BB*NPTS)     // 8192 total nodes
#define NF 14            // 2 + NS features in d1
#define CSPLIT 8
#define CS (NPTS / CSPLIT)   // 512 candidates per chunk

__device__ __forceinline__ float lrelu(float x) { return x >= 0.f ? x : 0.2f * x; }

// ---------------------------------------------------------------------------
// prep: copy d1 -> d1c and compute d2[n] = sum_f x[f]^2 (sequential order,
// identical to the in-loop ss accumulation of the round-0 passing kernel).
// ---------------------------------------------------------------------------
__global__ __launch_bounds__(256) void prep_kernel(const float* __restrict__ d1_in,
                                                   float* __restrict__ d1c,
                                                   float* __restrict__ d2a) {
  const int n = blockIdx.x * 256 + threadIdx.x;
  if (n >= NN) return;
  float v[NF];
#pragma unroll
  for (int f = 0; f < NF; ++f) v[f] = d1_in[(size_t)n * NF + f];
#pragma unroll
  for (int f = 0; f < NF; ++f) d1c[(size_t)n * NF + f] = v[f];
  float s = 0.f;
#pragma unroll
  for (int f = 0; f < NF; ++f) s += v[f] * v[f];
  d2a[n] = s;
}

// ---------------------------------------------------------------------------
// KNN partial: thread owns one row; candidates are WAVE-UNIFORM (scalar
// loads, no LDS). Each (row-block, chunk) block computes the row's top-8
// within candidates [chunk*CS, (chunk+1)*CS). Strict < insertion is correct
// because candidates are processed in increasing index order (ties keep the
// earlier = smaller index, matching jax.lax.top_k).
// dist = d2n + d2m - 2*dot, all terms bit-identical to the passing kernel.
// ---------------------------------------------------------------------------
__global__ __launch_bounds__(256) void knn_part_kernel(const float* __restrict__ d1c,
                                                       const float* __restrict__ d2a,
                                                       float* __restrict__ pd,
                                                       int* __restrict__ pi) {
  const int r = blockIdx.x * 256 + threadIdx.x;   // global row 0..NN-1
  const int b = r >> 12;
  const int rl = r & (NPTS - 1);
  const int chunk = blockIdx.y;
  const float* __restrict__ X  = d1c + (size_t)b * NPTS * NF;
  const float* __restrict__ D2 = d2a + (size_t)b * NPTS;

  float xr[NF];
#pragma unroll
  for (int f = 0; f < NF; ++f) xr[f] = X[rl * NF + f];
  const float d2n = D2[rl];

  float bd[8]; int bi[8];
#pragma unroll
  for (int p = 0; p < 8; ++p) { bd[p] = FLT_MAX; bi[p] = 0x7fffffff; }

  const int m0 = chunk * CS;
#pragma unroll 2
  for (int mm = 0; mm < CS; ++mm) {
    const int m = m0 + mm;                 // wave-uniform
    const float* cp = X + m * NF;          // uniform address -> scalar loads
    float dot = 0.f;
#pragma unroll
    for (int f = 0; f < NF; ++f) dot += xr[f] * cp[f];
    const float d2m = D2[m];               // uniform -> scalar load
    const float dist = d2n + d2m - 2.0f * dot;
    if (dist < bd[7] && m != rl) {
      float cd = dist; int ci = m;
#pragma unroll
      for (int p = 0; p < 8; ++p) {
        const bool lt = (cd < bd[p]);
        if (lt) { float td = bd[p]; int ti = bi[p]; bd[p] = cd; bi[p] = ci; cd = td; ci = ti; }
      }
    }
  }

  const size_t pb = ((size_t)chunk * NN + r) * 8;
#pragma unroll
  for (int p = 0; p < 8; ++p) { pd[pb + p] = bd[p]; pi[pb + p] = bi[p]; }
}

// ---------------------------------------------------------------------------
// KNN merge: per row, merge 8 sorted partial lists (chunk order = increasing
// candidate index) into the final top-8. Strict < keeps earlier index on tie.
// ---------------------------------------------------------------------------
__global__ __launch_bounds__(256) void knn_merge_kernel(const float* __restrict__ pd,
                                                        const int* __restrict__ pi,
                                                        int* __restrict__ idxo) {
  const int r = blockIdx.x * 256 + threadIdx.x;
  if (r >= NN) return;
  const int b = r >> 12;

  float bd[8]; int bi[8];
#pragma unroll
  for (int p = 0; p < 8; ++p) { bd[p] = FLT_MAX; bi[p] = 0x7fffffff; }

  for (int c = 0; c < CSPLIT; ++c) {
    const size_t pb = ((size_t)c * NN + r) * 8;
#pragma unroll 1
    for (int k = 0; k < 8; ++k) {
      const float d = pd[pb + k];
      if (d >= bd[7]) break;               // sorted ascending: rest can't enter
      const int ii = pi[pb + k];
      float cd = d; int ci = ii;
#pragma unroll
      for (int p = 0; p < 8; ++p) {
        const bool lt = (cd < bd[p]);
        if (lt) { float td = bd[p]; int ti = bi[p]; bd[p] = cd; bi[p] = ci; cd = td; ci = ti; }
      }
    }
  }
#pragma unroll
  for (int p = 0; p < 8; ++p) idxo[(size_t)r * K_NN + p] = b * NPTS + bi[p];
}

// ---------------------------------------------------------------------------
// GAT projection, split one thread per (node, head): OS=2. All accumulation
// orders (h over f; attention dots over d within a head) are identical to the
// round-0 passing kernel.
// ---------------------------------------------------------------------------
template <int F, int DH>
__global__ __launch_bounds__(256) void proj_kernel(const float* __restrict__ x, int ldx,
                                                   const float* __restrict__ W,
                                                   const float* __restrict__ asrc,
                                                   const float* __restrict__ adst,
                                                   float* __restrict__ hout,
                                                   float* __restrict__ sdout) {
  constexpr int TWO_DH = 2 * DH;
  __shared__ float Wl[F * TWO_DH];
  __shared__ float asl[TWO_DH];
  __shared__ float adl[TWO_DH];
  for (int i = threadIdx.x; i < F * TWO_DH; i += 256) Wl[i] = W[i];
  for (int i = threadIdx.x; i < TWO_DH; i += 256) { asl[i] = asrc[i]; adl[i] = adst[i]; }
  __syncthreads();

  const int gid = blockIdx.x * 256 + threadIdx.x;
  const int n = gid >> 1;          // node
  const int hh = gid & 1;          // head
  if (n >= NN) return;

  float xv[F];
#pragma unroll
  for (int f = 0; f < F; ++f) xv[f] = x[(size_t)n * ldx + f];

  const int o0 = hh * DH;
  float h[DH];
#pragma unroll
  for (int j = 0; j < DH; ++j) {
    float acc = 0.f;
#pragma unroll
    for (int f = 0; f < F; ++f) acc += xv[f] * Wl[f * TWO_DH + o0 + j];
    h[j] = acc;
  }
  float sp = 0.f, tp = 0.f;
#pragma unroll
  for (int j = 0; j < DH; ++j) { sp += h[j] * asl[o0 + j]; tp += h[j] * adl[o0 + j]; }

#pragma unroll
  for (int j = 0; j < DH; ++j) hout[(size_t)n * TWO_DH + o0 + j] = h[j];

  // pair (lane, lane^1) hold head0/head1 of the same node
  const float so = __shfl_xor(sp, 1);
  const float to = __shfl_xor(tp, 1);
  if (hh == 0) {
    float4 sd = make_float4(sp, so, tp, to);
    *(float4*)&sdout[(size_t)n * 4] = sd;
  }
}

// ---------------------------------------------------------------------------
// GAT aggregation, split one thread per (node, output-chunk): DS chunks of
// PER = DH/DS outputs. Softmax (both heads) recomputed per chunk — order
// identical to round-0 kernel. Per-d accumulation chain over k identical.
// ---------------------------------------------------------------------------
template <int DH, int DS, bool LR>
__global__ __launch_bounds__(256) void agg_kernel(const float* __restrict__ h,
                                                  const float* __restrict__ sd,
                                                  const int* __restrict__ idx,
                                                  float* __restrict__ yout) {
  constexpr int PER = DH / DS;
  const int gid = blockIdx.x * 256 + threadIdx.x;
  const int n = gid / DS;
  const int dc = gid % DS;
  if (n >= NN) return;

  const float4 s4 = *(const float4*)&sd[(size_t)n * 4];
  const float s0 = s4.x, s1 = s4.y;

  int jj[K_NN];
#pragma unroll
  for (int k = 0; k < K_NN; ++k) jj[k] = idx[(size_t)n * K_NN + k];

  float e0[K_NN], e1[K_NN];
#pragma unroll
  for (int k = 0; k < K_NN; ++k) {
    const float4 t4 = *(const float4*)&sd[(size_t)jj[k] * 4];
    e0[k] = lrelu(s0 + t4.z);
    e1[k] = lrelu(s1 + t4.w);
  }
  float m0 = -FLT_MAX, m1 = -FLT_MAX;
#pragma unroll
  for (int k = 0; k < K_NN; ++k) { m0 = fmaxf(m0, e0[k]); m1 = fmaxf(m1, e1[k]); }
  float w0[K_NN], w1[K_NN], S0 = 0.f, S1 = 0.f;
#pragma unroll
  for (int k = 0; k < K_NN; ++k) {
    w0[k] = __expf(e0[k] - m0); S0 += w0[k];
    w1[k] = __expf(e1[k] - m1); S1 += w1[k];
  }
  const float r0 = 0.5f / S0, r1 = 0.5f / S1;

  const int d0 = dc * PER;
  float y[PER];
#pragma unroll
  for (int d = 0; d < PER; ++d) y[d] = 0.f;
#pragma unroll
  for (int k = 0; k < K_NN; ++k) {
    const float* hj = h + (size_t)jj[k] * 2 * DH + d0;
    const float a0 = w0[k] * r0, a1 = w1[k] * r1;
#pragma unroll
    for (int d = 0; d < PER; ++d) y[d] += a0 * hj[d] + a1 * hj[DH + d];
  }
#pragma unroll
  for (int d = 0; d < PER; ++d) yout[(size_t)n * DH + d0 + d] = LR ? lrelu(y[d]) : y[d];
}

// ---------------------------------------------------------------------------
// Gumbel hard-select (argmax of logits+g; softmax is monotone).
// ---------------------------------------------------------------------------
__global__ __launch_bounds__(256) void sel_kernel(const float* __restrict__ d1c,
                                                  const float* __restrict__ w1o,
                                                  const float* __restrict__ gum,
                                                  int blk, float* __restrict__ out,
                                                  float* __restrict__ x12,
                                                  float* __restrict__ x1f, int writeX1f) {
  const int n = blockIdx.x * 256 + threadIdx.x;
  if (n >= NN) return;
  const int b = n >> 12, nl = n & (NPTS - 1);
  const float* g1 = gum + (((size_t)(blk * 2 + 0) * BB + b) * NPTS + nl) * NG;
  const float* g2 = gum + (((size_t)(blk * 2 + 1) * BB + b) * NPTS + nl) * NG;
  const float* w = w1o + (size_t)n * NS;
  const float* dr = d1c + (size_t)n * NF;

  float best1 = -FLT_MAX, best2 = -FLT_MAX;
  int a1 = 0, a2 = 0;
#pragma unroll
  for (int a = 0; a < NG; ++a) {
    float l1 = w[2 * a] + g1[a];
    if (l1 > best1) { best1 = l1; a1 = a; }
    float l2 = w[2 * a + 1] + g2[a];
    if (l2 > best2) { best2 = l2; a2 = a; }
  }
  const float x1 = dr[2 + 2 * a1];
  const float x2 = dr[3 + 2 * a2];

  const size_t ob = (((size_t)blk * BB + b) * NPTS + nl) * 2;
  out[ob + 0] = x1;
  out[ob + 1] = x2;
  x12[n * 2 + 0] = x1;
  x12[n * 2 + 1] = x2;

  if (writeX1f) {
#pragma unroll
    for (int g = 0; g < NG; ++g) {
      x1f[(size_t)n * NS + 2 * g]     = fabsf(dr[2 + 2 * g] - x1);
      x1f[(size_t)n * NS + 2 * g + 1] = fabsf(dr[3 + 2 * g] - x2);
    }
  }
}

// ---------------------------------------------------------------------------
// d1 update + d2 recompute for the next KNN (sequential over f=0..13,
// matching prep_kernel's order).
// ---------------------------------------------------------------------------
__global__ __launch_bounds__(256) void combine_kernel(float* __restrict__ d1c,
                                                      const float* __restrict__ xws,
                                                      const float* __restrict__ dws,
                                                      const float* __restrict__ x12,
                                                      float* __restrict__ d2a) {
  const int n = blockIdx.x * 256 + threadIdx.x;
  if (n >= NN) return;
  const float x1 = x12[n * 2 + 0], x2 = x12[n * 2 + 1];
  float* dr = d1c + (size_t)n * NF;
  const float xy0 = dr[0], xy1 = dr[1];
  float nd[NS];
#pragma unroll
  for (int c = 0; c < NS; ++c) {
    const float a = xws[(size_t)n * NS + c];
    const float dd = dws[(size_t)n * NS + c];
    const float m = fmaxf(a, dd);
    const float ea = __expf(a - m), ed = __expf(dd - m);
    const float inv = 1.f / (ea + ed);
    const float ch0 = (c & 1) ? x2 : x1;
    nd[c] = (ea * inv) * ch0 + (ed * inv) * dr[2 + c];
  }
#pragma unroll
  for (int c = 0; c < NS; ++c) dr[2 + c] = nd[c];
  float s = 0.f;
  s += xy0 * xy0;
  s += xy1 * xy1;
#pragma unroll
  for (int c = 0; c < NS; ++c) s += nd[c] * nd[c];
  d2a[n] = s;
}

// ---------------------------------------------------------------------------
extern "C" void kernel_launch(void* const* d_in, const int* in_sizes, int n_in,
                              void* d_out, int out_size, void* d_ws, size_t ws_size,
                              hipStream_t stream) {
  const float* d1_in = (const float*)d_in[0];
  const float* gum   = (const float*)d_in[1];
  const float* W1    = (const float*)d_in[2];
  const float* a1s   = (const float*)d_in[3];
  const float* a1d   = (const float*)d_in[4];
  const float* W2    = (const float*)d_in[5];
  const float* a2s   = (const float*)d_in[6];
  const float* a2d   = (const float*)d_in[7];
  float* out = (float*)d_out;

  // Workspace partition (floats). Total ~6.1 MB.
  float* ws     = (float*)d_ws;
  float* d1c    = ws;                         // 8192*14   = 114688
  int*   idxb   = (int*)(ws + 114688);        // 8192*8    = 65536 ints
  float* d2a    = ws + 114688 + 65536;        // 8192
  float* hbuf   = d2a + 8192;                 // 8192*64   = 524288
  float* sdb    = hbuf + 524288;              // 8192*4    = 32768
  float* ybuf   = sdb + 32768;                // 8192*32   = 262144
  float* feats  = ybuf + 262144;              // 98304
  float* bufw1  = feats + 98304;              // 98304  (w1 logits / x_ws)
  float* bufxfi = bufw1 + 98304;              // 98304  (x1f_in)
  float* bufxf  = bufxfi + 98304;             // 98304  (xf)
  float* bufdws = bufxf + 98304;              // 98304  (d_ws)
  float* x12    = bufdws + 98304;             // 16384

  // KNN partial scratch aliases onto fe-scratch (dead at KNN time):
  // pd = hbuf (524288 floats), pi spans ybuf..bufxfi (>=524288 ints).
  float* pd = hbuf;
  int*   pi = (int*)ybuf;

  const int NB = NN / 256;  // 32

  prep_kernel<<<NB, 256, 0, stream>>>(d1_in, d1c, d2a);

  auto run_fe = [&](const float* xin, int ldx, int m, float* yout, bool lrelu_out) {
    proj_kernel<12, 32><<<NB * 2, 256, 0, stream>>>(xin, ldx, W1 + (size_t)m * 768,
                                                    a1s + (size_t)m * 64, a1d + (size_t)m * 64,
                                                    hbuf, sdb);
    agg_kernel<32, 8, true><<<NB * 8, 256, 0, stream>>>(hbuf, sdb, idxb, ybuf);
    proj_kernel<32, 12><<<NB * 2, 256, 0, stream>>>(ybuf, 32, W2 + (size_t)m * 768,
                                                    a2s + (size_t)m * 24, a2d + (size_t)m * 24,
                                                    hbuf, sdb);
    if (lrelu_out)
      agg_kernel<12, 4, true><<<NB * 4, 256, 0, stream>>>(hbuf, sdb, idxb, yout);
    else
      agg_kernel<12, 4, false><<<NB * 4, 256, 0, stream>>>(hbuf, sdb, idxb, yout);
  };

  for (int i = 0; i < NBLOCK; ++i) {
    knn_part_kernel<<<dim3(NB, CSPLIT), 256, 0, stream>>>(d1c, d2a, pd, pi);
    knn_merge_kernel<<<NB, 256, 0, stream>>>(pd, pi, idxb);
    run_fe(d1c + 2, NF, 2 * i, feats, true);          // feats = lrelu(fe(d1[:,2:]))
    run_fe(feats, NS, 2 * i + 1, bufw1, false);       // w1 logits
    sel_kernel<<<NB, 256, 0, stream>>>(d1c, bufw1, gum, i, out, x12, bufxfi,
                                       (i < NBLOCK - 1) ? 1 : 0);
    if (i == NBLOCK - 1) break;
    run_fe(bufxfi, NS, 6 + 3 * i, bufxf, true);       // xf = lrelu(fe(x1f_in))
    run_fe(bufxf, NS, 6 + 3 * i + 1, bufw1, false);   // x_ws
    run_fe(feats, NS, 6 + 3 * i + 2, bufdws, false);  // d_ws
    combine_kernel<<<NB, 256, 0, stream>>>(d1c, bufw1, bufdws, x12, d2a);
  }
}